// Round 4
// baseline (229.909 us; speedup 1.0000x reference)
//
#include <hip/hip_runtime.h>
#include <hip/hip_bf16.h>

// Cross-attention B=8, S_ENC=2048, S_DEC=1024, D=512, U=512.
// R13: R12 fusion (score+softmax, S in registers) with ONE fix: the Q-staging
// global_load_lds destination must be WAVE-UNIFORM (HW writes base + lane*16;
// divergent LDS ptr is UB -> garbled Q tile -> R12's allclose failure). All
// other code identical to R12 (proj/pv R11 counted-vmcnt form).
//
// ws: qh [0,8M) | kh [8M,24M) | vt [32M,48M) | P [48M,80M) fp16 |
//     dech @48M (dead pre-P) | wts @56M (dead pre-P) | ench @112M (dead after proj)

typedef __attribute__((ext_vector_type(8))) _Float16 f16x8;
typedef __attribute__((ext_vector_type(4))) _Float16 f16x4;
typedef __attribute__((ext_vector_type(4))) float f32x4;

#define MFMA16(a, b, c) __builtin_amdgcn_mfma_f32_16x16x32_f16(a, b, c, 0, 0, 0)
#define L2E 1.44269504088896f

__device__ __forceinline__ void glds16(const void* g, void* l) {
    __builtin_amdgcn_global_load_lds(
        (const __attribute__((address_space(1))) void*)g,
        (__attribute__((address_space(3))) void*)l, 16, 0, 0);
}

// prep: blocks [0,4096) enc cvt, [4096,6144) dec cvt, [6144,6336) W transpose.
__global__ __launch_bounds__(256) void prep_kernel(
    const float* __restrict__ enc, const float* __restrict__ dec,
    const float* __restrict__ Wq, const float* __restrict__ Wk,
    const float* __restrict__ Wv, _Float16* __restrict__ oenc,
    _Float16* __restrict__ odec, _Float16* __restrict__ planes) {
    const int bid = blockIdx.x;
    if (bid < 6144) {
        const float* x;
        _Float16* o;
        size_t i;
        if (bid < 4096) { x = enc; o = oenc; i = ((size_t)bid * 256 + threadIdx.x) * 8; }
        else { x = dec; o = odec; i = ((size_t)(bid - 4096) * 256 + threadIdx.x) * 8; }
        float4 a0 = *(const float4*)(x + i);
        float4 a1 = *(const float4*)(x + i + 4);
        float v[8] = {a0.x, a0.y, a0.z, a0.w, a1.x, a1.y, a1.z, a1.w};
        f16x8 h;
#pragma unroll
        for (int j = 0; j < 8; ++j) h[j] = (_Float16)v[j];
        *(f16x8*)(o + i) = h;
        return;
    }
    const int t = bid - 6144;
    const int zw = t >> 6, r = t & 63;
    const int u0 = (r & 7) * 64, d0 = (r >> 3) * 64;
    const float* W = zw == 0 ? Wq : (zw == 1 ? Wk : Wv);
    _Float16* ot = planes + (size_t)zw * 262144;
    __shared__ float T[64][65];
    const int tr = threadIdx.x >> 4, tc = (threadIdx.x & 15) * 4;
#pragma unroll
    for (int j = 0; j < 4; ++j) {
        float4 vv = *(const float4*)(W + (size_t)(d0 + tr + j * 16) * 512 + u0 + tc);
        T[tr + j * 16][tc + 0] = vv.x;
        T[tr + j * 16][tc + 1] = vv.y;
        T[tr + j * 16][tc + 2] = vv.z;
        T[tr + j * 16][tc + 3] = vv.w;
    }
    __syncthreads();
#pragma unroll
    for (int j = 0; j < 4; ++j) {
        int ul = tr + j * 16;
        f16x4 h;
#pragma unroll
        for (int i = 0; i < 4; ++i) h[i] = (_Float16)T[tc + i][ul];
        *(f16x4*)(ot + (size_t)(u0 + ul) * 512 + d0 + tc) = h;
    }
}

// Unified projections (R11 form): 64x256 tiles, K=512, dbuf LDS, glds-16,
// swizzled, counted-vmcnt.
__global__ __launch_bounds__(256) void proj_kernel(
    const _Float16* __restrict__ dech, const _Float16* __restrict__ ench,
    const _Float16* __restrict__ wts, _Float16* __restrict__ qh,
    _Float16* __restrict__ kh, _Float16* __restrict__ vt) {
    __shared__ __align__(16) char smem[40960];
    const int bid = blockIdx.x;
    int seg, bx, by;
    if (bid < 256) { seg = 0; by = bid & 127; bx = bid >> 7; }
    else if (bid < 768) { int t = bid - 256; seg = 1; by = t & 255; bx = t >> 8; }
    else { int t = bid - 768; seg = 2; by = t & 255; bx = t >> 8; }
    const _Float16* A = seg == 0 ? dech : ench;
    const _Float16* Bp = wts + (size_t)seg * 262144;

    const int tid = threadIdx.x;
    const int wave = tid >> 6, lane = tid & 63;
    const int quad = lane >> 4, m16 = lane & 15;
    const int wr = wave >> 1, wc = wave & 1;
    const int row0 = by * 64, col0 = bx * 256;

    const int scol = ((lane & 3) ^ ((lane >> 3) & 3)) * 8;
    const int srowA = wave * 16 + (lane >> 2);
    const int srowB = wave * 64 + (lane >> 2);
    const _Float16* agp = A + (size_t)(row0 + srowA) * 512 + scol;
    const _Float16* bgp = Bp + (size_t)(col0 + srowB) * 512 + scol;
    const int ldsAoff = wave * 1024;
    const int ldsBoff = 4096 + wave * 4096;

    f32x4 acc[2][8];
#pragma unroll
    for (int mt = 0; mt < 2; ++mt)
#pragma unroll
        for (int nt = 0; nt < 8; ++nt) acc[mt][nt] = (f32x4){0.f, 0.f, 0.f, 0.f};

    auto stage = [&](int i, int buf) {
        char* base = smem + buf * 20480;
        const int k0 = i * 32;
        glds16(agp + k0, base + ldsAoff);
#pragma unroll
        for (int j = 0; j < 4; ++j)
            glds16(bgp + k0 + j * 16 * 512, base + ldsBoff + j * 1024);
    };

    const int csw = (quad ^ ((lane >> 1) & 3)) * 16;

    stage(0, 0);
    for (int i = 0; i < 16; ++i) {
        __builtin_amdgcn_s_barrier();
        if (i + 1 < 16) {
            stage(i + 1, (i + 1) & 1);
            asm volatile("s_waitcnt vmcnt(5)" ::: "memory");
        } else {
            asm volatile("s_waitcnt vmcnt(0)" ::: "memory");
        }
        __builtin_amdgcn_s_barrier();
        const char* bb = smem + (i & 1) * 20480;
        const char* pa = bb + (wr * 32 + m16) * 64 + csw;
        const char* pb = bb + 4096 + (wc * 128 + m16) * 64 + csw;
        f16x8 af[2];
#pragma unroll
        for (int mt = 0; mt < 2; ++mt) af[mt] = *(const f16x8*)(pa + mt * 1024);
#pragma unroll
        for (int nt = 0; nt < 8; ++nt) {
            f16x8 bf = *(const f16x8*)(pb + nt * 1024);
#pragma unroll
            for (int mt = 0; mt < 2; ++mt) acc[mt][nt] = MFMA16(af[mt], bf, acc[mt][nt]);
        }
    }

    if (seg < 2) {
        _Float16* o = seg == 0 ? qh : kh;
#pragma unroll
        for (int mt = 0; mt < 2; ++mt)
#pragma unroll
            for (int nt = 0; nt < 8; ++nt)
#pragma unroll
                for (int rr = 0; rr < 4; ++rr) {
                    int row = row0 + wr * 32 + mt * 16 + quad * 4 + rr;
                    int col = col0 + wc * 128 + nt * 16 + m16;
                    o[(size_t)row * 512 + col] = (_Float16)acc[mt][nt][rr];
                }
    } else {
        __syncthreads();
        char* reg = smem + wave * 8192;
#pragma unroll
        for (int nt = 0; nt < 8; ++nt)
#pragma unroll
            for (int mt = 0; mt < 2; ++mt) {
                f16x4 pk;
#pragma unroll
                for (int rr = 0; rr < 4; ++rr) pk[rr] = (_Float16)acc[mt][nt][rr];
                *(f16x4*)(reg + (nt * 16 + m16) * 64 + (mt * 16 + quad * 4) * 2) = pk;
            }
        const int b = row0 >> 11;
        const int s_base = (row0 & 2047) + wr * 32;
        const int u_base = col0 + wc * 128;
        __syncthreads();
#pragma unroll
        for (int j = 0; j < 8; ++j) {
            int n = j * 16 + (lane >> 2);
            int mo = (lane & 3) * 8;
            f16x8 val = *(const f16x8*)(reg + n * 64 + mo * 2);
            *(f16x8*)(vt + (size_t)(b * 512 + u_base + n) * 2048 + s_base + mo) = val;
        }
    }
}

// Fused score+softmax. Grid 256 x 512 thr. Block (bid): batch = bid&7 (XCD
// pin -> kh[b] 2MB L2-resident), qt = bid>>3. Block owns q-rows
// [batch*1024 + qt*32, +32) x all 2048 k. Wave w: k-slice [w*256,+256).
// acc[2][16] f32x4 (S in regs). Q in LDS (32KB, XOR-swizzled, staged once,
// WAVE-UNIFORM glds dest); K-frags direct from global. Softmax exact.
__global__ __launch_bounds__(512) void score_softmax_kernel(
    const _Float16* __restrict__ qh, const _Float16* __restrict__ kh,
    _Float16* __restrict__ P) {
    __shared__ __align__(16) char smem[35072];
    // [0,32768): Q tiles: [16 dsteps][32 q][64B], chunk-swizzled
    // [32768,+1024): per-wave max partials [8][32] f32
    // [33792,+128): gmax[32]
    // [33920,+1024): per-wave sum partials [8][32]
    // [34944,+128): ginv[32]
    const int bid = blockIdx.x;
    const int batch = bid & 7, qt = bid >> 3;
    const int row0 = batch * 1024 + qt * 32;
    const int tid = threadIdx.x;
    const int wave = tid >> 6, lane = tid & 63;
    const int quad = lane >> 4, m16 = lane & 15;

    // --- stage Q (32 rows x 512 d fp16 = 32KB), pre-swizzled source,
    //     wave-uniform LDS dest (HW writes base + lane*16) ---
    {
        const int scol = ((lane & 3) ^ ((lane >> 3) & 3)) * 8;
#pragma unroll
        for (int t = 0; t < 2; ++t) {
            const int d = wave * 2 + t;
#pragma unroll
            for (int j = 0; j < 2; ++j) {
                const int srow = j * 16 + (lane >> 2);
                glds16(qh + (size_t)(row0 + srow) * 512 + d * 32 + scol,
                       smem + d * 2048 + j * 1024);
            }
        }
    }
    __syncthreads();  // drains vmcnt(0); Q visible to all

    f32x4 acc[2][16];
#pragma unroll
    for (int mt = 0; mt < 2; ++mt)
#pragma unroll
        for (int nt = 0; nt < 16; ++nt) acc[mt][nt] = (f32x4){0.f, 0.f, 0.f, 0.f};

    const int kb = wave * 256;
    const _Float16* __restrict__ kbase =
        kh + (size_t)(batch * 2048 + kb + m16) * 512 + quad * 8;
    const int csw = (quad ^ ((m16 >> 1) & 3)) * 16;

    for (int d = 0; d < 16; ++d) {
        const char* pa = smem + d * 2048 + m16 * 64 + csw;
        f16x8 a0 = *(const f16x8*)(pa);
        f16x8 a1 = *(const f16x8*)(pa + 1024);
#pragma unroll
        for (int nt = 0; nt < 16; ++nt) {
            f16x8 bf = *(const f16x8*)(kbase + nt * 16 * 512 + d * 32);
            acc[0][nt] = MFMA16(a0, bf, acc[0][nt]);
            acc[1][nt] = MFMA16(a1, bf, acc[1][nt]);
        }
    }

    // --- softmax ---
    float rmax[2][4];
#pragma unroll
    for (int mt = 0; mt < 2; ++mt)
#pragma unroll
        for (int rr = 0; rr < 4; ++rr) {
            float m = acc[mt][0][rr];
#pragma unroll
            for (int nt = 1; nt < 16; ++nt) m = fmaxf(m, acc[mt][nt][rr]);
#pragma unroll
            for (int off = 1; off < 16; off <<= 1) m = fmaxf(m, __shfl_xor(m, off));
            rmax[mt][rr] = m;
        }
    float* maxp = (float*)(smem + 32768);
    float* gmax = (float*)(smem + 33792);
    float* sump = (float*)(smem + 33920);
    float* ginv = (float*)(smem + 34944);
    if (m16 == 0) {
#pragma unroll
        for (int mt = 0; mt < 2; ++mt)
#pragma unroll
            for (int rr = 0; rr < 4; ++rr)
                maxp[wave * 32 + mt * 16 + quad * 4 + rr] = rmax[mt][rr];
    }
    __syncthreads();
    if (tid < 32) {
        float g = maxp[tid];
#pragma unroll
        for (int w = 1; w < 8; ++w) g = fmaxf(g, maxp[w * 32 + tid]);
        gmax[tid] = g;
    }
    __syncthreads();
    float gm[2][4];
#pragma unroll
    for (int mt = 0; mt < 2; ++mt)
#pragma unroll
        for (int rr = 0; rr < 4; ++rr) gm[mt][rr] = gmax[mt * 16 + quad * 4 + rr];
    float rsum[2][4];
#pragma unroll
    for (int mt = 0; mt < 2; ++mt)
#pragma unroll
        for (int rr = 0; rr < 4; ++rr) rsum[mt][rr] = 0.f;
#pragma unroll
    for (int mt = 0; mt < 2; ++mt)
#pragma unroll
        for (int nt = 0; nt < 16; ++nt)
#pragma unroll
            for (int rr = 0; rr < 4; ++rr) {
                float e = exp2f((acc[mt][nt][rr] - gm[mt][rr]) * L2E);
                acc[mt][nt][rr] = e;
                rsum[mt][rr] += e;
            }
#pragma unroll
    for (int mt = 0; mt < 2; ++mt)
#pragma unroll
        for (int rr = 0; rr < 4; ++rr) {
#pragma unroll
            for (int off = 1; off < 16; off <<= 1)
                rsum[mt][rr] += __shfl_xor(rsum[mt][rr], off);
        }
    if (m16 == 0) {
#pragma unroll
        for (int mt = 0; mt < 2; ++mt)
#pragma unroll
            for (int rr = 0; rr < 4; ++rr)
                sump[wave * 32 + mt * 16 + quad * 4 + rr] = rsum[mt][rr];
    }
    __syncthreads();
    if (tid < 32) {
        float s = sump[tid];
#pragma unroll
        for (int w = 1; w < 8; ++w) s += sump[w * 32 + tid];
        ginv[tid] = 1.0f / s;
    }
    __syncthreads();
#pragma unroll
    for (int mt = 0; mt < 2; ++mt)
#pragma unroll
        for (int rr = 0; rr < 4; ++rr) {
            const float iv = ginv[mt * 16 + quad * 4 + rr];
            const size_t ro =
                (size_t)(row0 + mt * 16 + quad * 4 + rr) * 2048 + kb + m16;
#pragma unroll
            for (int nt = 0; nt < 16; ++nt)
                P[ro + nt * 16] = (_Float16)(acc[mt][nt][rr] * iv);
        }
}

// PV GEMM (R11 form), 64q x 128u tiles, batch-pinned, swizzled, counted vmcnt.
__global__ __launch_bounds__(256) void pv_kernel(
    const _Float16* __restrict__ P, const _Float16* __restrict__ vt,
    float* __restrict__ out) {
    __shared__ __align__(16) char smem[24576];
    const int b = blockIdx.x;
    const int z = b & 7, r = b >> 3;
    const int by = r >> 2, bx = r & 3;
    const int tid = threadIdx.x;
    const int wave = tid >> 6, lane = tid & 63;
    const int quad = lane >> 4, m16 = lane & 15;
    const int wr = wave >> 1, wc = wave & 1;
    const int row0 = z * 1024 + by * 64;
    const int col0 = bx * 128;

    const int scol = ((lane & 3) ^ ((lane >> 3) & 3)) * 8;
    const int srowA = wave * 16 + (lane >> 2);
    const int srowB = wave * 32 + (lane >> 2);
    const _Float16* agp = P + (size_t)(row0 + srowA) * 2048 + scol;
    const _Float16* bgp = vt + (size_t)(z * 512 + col0 + srowB) * 2048 + scol;
    const int ldsAoff = wave * 1024;
    const int ldsBoff = 4096 + wave * 2048;

    f32x4 acc[2][4];
#pragma unroll
    for (int mt = 0; mt < 2; ++mt)
#pragma unroll
        for (int nt = 0; nt < 4; ++nt) acc[mt][nt] = (f32x4){0.f, 0.f, 0.f, 0.f};

    auto stage = [&](int i, int buf) {
        char* base = smem + buf * 12288;
        const int k0 = i * 32;
        glds16(agp + k0, base + ldsAoff);
#pragma unroll
        for (int j = 0; j < 2; ++j)
            glds16(bgp + k0 + j * 16 * 2048, base + ldsBoff + j * 1024);
    };

    const int csw = (quad ^ ((lane >> 1) & 3)) * 16;

    stage(0, 0);
    for (int i = 0; i < 64; ++i) {
        __builtin_amdgcn_s_barrier();
        if (i + 1 < 64) {
            stage(i + 1, (i + 1) & 1);
            asm volatile("s_waitcnt vmcnt(3)" ::: "memory");
        } else {
            asm volatile("s_waitcnt vmcnt(0)" ::: "memory");
        }
        __builtin_amdgcn_s_barrier();
        const char* bb = smem + (i & 1) * 12288;
        const char* pa = bb + (wr * 32 + m16) * 64 + csw;
        const char* pb = bb + 4096 + (wc * 64 + m16) * 64 + csw;
        f16x8 af[2];
#pragma unroll
        for (int mt = 0; mt < 2; ++mt) af[mt] = *(const f16x8*)(pa + mt * 1024);
#pragma unroll
        for (int nt = 0; nt < 4; ++nt) {
            f16x8 bf = *(const f16x8*)(pb + nt * 1024);
#pragma unroll
            for (int mt = 0; mt < 2; ++mt) acc[mt][nt] = MFMA16(af[mt], bf, acc[mt][nt]);
        }
    }

#pragma unroll
    for (int mt = 0; mt < 2; ++mt)
#pragma unroll
        for (int nt = 0; nt < 4; ++nt)
#pragma unroll
            for (int rr = 0; rr < 4; ++rr) {
                int row = row0 + wr * 32 + mt * 16 + quad * 4 + rr;
                int col = col0 + wc * 64 + nt * 16 + m16;
                out[(size_t)row * 512 + col] = acc[mt][nt][rr];
            }
}

extern "C" void kernel_launch(void* const* d_in, const int* in_sizes, int n_in,
                              void* d_out, int out_size, void* d_ws, size_t ws_size,
                              hipStream_t stream) {
    const float* enc = (const float*)d_in[0];  // [8,2048,512]
    const float* dec = (const float*)d_in[1];  // [8,1024,512]
    const float* Wq = (const float*)d_in[2];   // [512,512]
    const float* Wk = (const float*)d_in[3];
    const float* Wv = (const float*)d_in[4];
    float* out = (float*)d_out;                // [8,1024,512] fp32

    char* ws = (char*)d_ws;
    _Float16* qh = (_Float16*)(ws);
    _Float16* kh = (_Float16*)(ws + ((size_t)8 << 20));
    _Float16* vt = (_Float16*)(ws + ((size_t)32 << 20));
    _Float16* P = (_Float16*)(ws + ((size_t)48 << 20));     // 32MB fp16
    _Float16* dech = (_Float16*)(ws + ((size_t)48 << 20));  // dead before P written
    _Float16* wts = (_Float16*)(ws + ((size_t)56 << 20));   // dead before P written
    _Float16* ench = (_Float16*)(ws + ((size_t)112 << 20)); // dead after proj

    dim3 blk(256);
    prep_kernel<<<6336, blk, 0, stream>>>(enc, dec, Wq, Wk, Wv, ench, dech, wts);
    proj_kernel<<<1280, blk, 0, stream>>>(dech, ench, wts, qh, kh, vt);
    score_softmax_kernel<<<256, dim3(512), 0, stream>>>(qh, kh, P);
    pv_kernel<<<512, blk, 0, stream>>>(P, vt, out);
}

// Round 7
// 207.797 us; speedup vs baseline: 1.1064x; 1.1064x over previous
//
#include <hip/hip_runtime.h>
#include <hip/hip_bf16.h>

// Cross-attention B=8, S_ENC=2048, S_DEC=1024, D=512, U=512.
// R16: abandon the counted-vmcnt raw-barrier structure (R11 was a measured
// null vs R10, and two verbatim ports into it failed correctness -- raw
// s_barrier is not a compiler fence; m152-style race). Everything reverts to
// the R10 __syncthreads-fenced form (passed, 197.6us). ONE change vs R10:
// pv widened 64x128 -> 64x256 (verbatim R10-proj K-loop, stride 2048,
// 64 iters, 5 glds/wave/step, acc[2][8]) -- 2x MFMA per staged byte, halved
// P re-streaming. Grid 256: z=b&7 XCD pin; by=r>>1, bx=r&1 so both u-slabs
// of a q-tile share an XCD (P rows L2-shared).
//
// ws: qh [0,8M) | kh [8M,24M) | P [0,32M) (after score) | vt [32M,48M) |
//     S [48M,112M) fp32 | dech @48M (dead pre-S) | Wt @56M (dead pre-S) |
//     ench @112M (dead after proj)

typedef __attribute__((ext_vector_type(8))) _Float16 f16x8;
typedef __attribute__((ext_vector_type(4))) _Float16 f16x4;
typedef __attribute__((ext_vector_type(4))) float f32x4;

#define MFMA16(a, b, c) __builtin_amdgcn_mfma_f32_16x16x32_f16(a, b, c, 0, 0, 0)
#define L2E 1.44269504088896f

__device__ __forceinline__ void glds16(const void* g, void* l) {
    __builtin_amdgcn_global_load_lds(
        (const __attribute__((address_space(1))) void*)g,
        (__attribute__((address_space(3))) void*)l, 16, 0, 0);
}

// prep: blocks [0,4096) enc cvt, [4096,6144) dec cvt, [6144,6336) W transpose.
__global__ __launch_bounds__(256) void prep_kernel(
    const float* __restrict__ enc, const float* __restrict__ dec,
    const float* __restrict__ Wq, const float* __restrict__ Wk,
    const float* __restrict__ Wv, _Float16* __restrict__ oenc,
    _Float16* __restrict__ odec, _Float16* __restrict__ planes) {
    const int bid = blockIdx.x;
    if (bid < 6144) {
        const float* x;
        _Float16* o;
        size_t i;
        if (bid < 4096) { x = enc; o = oenc; i = ((size_t)bid * 256 + threadIdx.x) * 8; }
        else { x = dec; o = odec; i = ((size_t)(bid - 4096) * 256 + threadIdx.x) * 8; }
        float4 a0 = *(const float4*)(x + i);
        float4 a1 = *(const float4*)(x + i + 4);
        float v[8] = {a0.x, a0.y, a0.z, a0.w, a1.x, a1.y, a1.z, a1.w};
        f16x8 h;
#pragma unroll
        for (int j = 0; j < 8; ++j) h[j] = (_Float16)v[j];
        *(f16x8*)(o + i) = h;
        return;
    }
    const int t = bid - 6144;
    const int zw = t >> 6, r = t & 63;
    const int u0 = (r & 7) * 64, d0 = (r >> 3) * 64;
    const float* W = zw == 0 ? Wq : (zw == 1 ? Wk : Wv);
    _Float16* ot = planes + (size_t)zw * 262144;
    __shared__ float T[64][65];
    const int tr = threadIdx.x >> 4, tc = (threadIdx.x & 15) * 4;
#pragma unroll
    for (int j = 0; j < 4; ++j) {
        float4 vv = *(const float4*)(W + (size_t)(d0 + tr + j * 16) * 512 + u0 + tc);
        T[tr + j * 16][tc + 0] = vv.x;
        T[tr + j * 16][tc + 1] = vv.y;
        T[tr + j * 16][tc + 2] = vv.z;
        T[tr + j * 16][tc + 3] = vv.w;
    }
    __syncthreads();
#pragma unroll
    for (int j = 0; j < 4; ++j) {
        int ul = tr + j * 16;
        f16x4 h;
#pragma unroll
        for (int i = 0; i < 4; ++i) h[i] = (_Float16)T[tc + i][ul];
        *(f16x4*)(ot + (size_t)(u0 + ul) * 512 + d0 + tc) = h;
    }
}

// Unified projections (R10 form): 64x256 tiles, K=512, dbuf LDS, glds-16,
// swizzled, __syncthreads-fenced.
__global__ __launch_bounds__(256) void proj_kernel(
    const _Float16* __restrict__ dech, const _Float16* __restrict__ ench,
    const _Float16* __restrict__ wts, _Float16* __restrict__ qh,
    _Float16* __restrict__ kh, _Float16* __restrict__ vt) {
    __shared__ __align__(16) char smem[40960];
    const int bid = blockIdx.x;
    int seg, bx, by;
    if (bid < 256) { seg = 0; by = bid & 127; bx = bid >> 7; }
    else if (bid < 768) { int t = bid - 256; seg = 1; by = t & 255; bx = t >> 8; }
    else { int t = bid - 768; seg = 2; by = t & 255; bx = t >> 8; }
    const _Float16* A = seg == 0 ? dech : ench;
    const _Float16* Bp = wts + (size_t)seg * 262144;

    const int tid = threadIdx.x;
    const int wave = tid >> 6, lane = tid & 63;
    const int quad = lane >> 4, m16 = lane & 15;
    const int wr = wave >> 1, wc = wave & 1;
    const int row0 = by * 64, col0 = bx * 256;

    // source pre-swizzle: lane L feeds LDS slot (r=L>>2, c=L&3); slot c must
    // hold global chunk c ^ ((r>>1)&3) -> read chunk (L&3)^((L>>3)&3).
    const int scol = ((lane & 3) ^ ((lane >> 3) & 3)) * 8;
    const int srowA = wave * 16 + (lane >> 2);
    const int srowB = wave * 64 + (lane >> 2);
    const _Float16* agp = A + (size_t)(row0 + srowA) * 512 + scol;
    const _Float16* bgp = Bp + (size_t)(col0 + srowB) * 512 + scol;
    const int ldsAoff = wave * 1024;
    const int ldsBoff = 4096 + wave * 4096;

    f32x4 acc[2][8];
#pragma unroll
    for (int mt = 0; mt < 2; ++mt)
#pragma unroll
        for (int nt = 0; nt < 8; ++nt) acc[mt][nt] = (f32x4){0.f, 0.f, 0.f, 0.f};

    auto stage = [&](int i, int buf) {
        char* base = smem + buf * 20480;
        const int k0 = i * 32;
        glds16(agp + k0, base + ldsAoff);
#pragma unroll
        for (int j = 0; j < 4; ++j)
            glds16(bgp + k0 + j * 16 * 512, base + ldsBoff + j * 1024);
    };

    // swizzled read slot: chunk quad of row (…+m16) sits at slot quad^((m16>>1)&3)
    const int csw = (quad ^ ((lane >> 1) & 3)) * 16;

    stage(0, 0);
    for (int i = 0; i < 16; ++i) {
        __syncthreads();
        if (i + 1 < 16) stage(i + 1, (i + 1) & 1);
        const char* bb = smem + (i & 1) * 20480;
        const char* pa = bb + (wr * 32 + m16) * 64 + csw;
        const char* pb = bb + 4096 + (wc * 128 + m16) * 64 + csw;
        f16x8 af[2];
#pragma unroll
        for (int mt = 0; mt < 2; ++mt) af[mt] = *(const f16x8*)(pa + mt * 1024);
#pragma unroll
        for (int nt = 0; nt < 8; ++nt) {
            f16x8 bf = *(const f16x8*)(pb + nt * 1024);
#pragma unroll
            for (int mt = 0; mt < 2; ++mt) acc[mt][nt] = MFMA16(af[mt], bf, acc[mt][nt]);
        }
    }

    if (seg < 2) {
        _Float16* o = seg == 0 ? qh : kh;
#pragma unroll
        for (int mt = 0; mt < 2; ++mt)
#pragma unroll
            for (int nt = 0; nt < 8; ++nt)
#pragma unroll
                for (int rr = 0; rr < 4; ++rr) {
                    int row = row0 + wr * 32 + mt * 16 + quad * 4 + rr;
                    int col = col0 + wc * 128 + nt * 16 + m16;
                    o[(size_t)row * 512 + col] = (_Float16)acc[mt][nt][rr];
                }
    } else {
        __syncthreads();
        char* reg = smem + wave * 8192;  // [128 n][32 m] fp16 per-wave scratch
#pragma unroll
        for (int nt = 0; nt < 8; ++nt)
#pragma unroll
            for (int mt = 0; mt < 2; ++mt) {
                f16x4 pk;
#pragma unroll
                for (int rr = 0; rr < 4; ++rr) pk[rr] = (_Float16)acc[mt][nt][rr];
                *(f16x4*)(reg + (nt * 16 + m16) * 64 + (mt * 16 + quad * 4) * 2) = pk;
            }
        const int b = row0 >> 11;
        const int s_base = (row0 & 2047) + wr * 32;
        const int u_base = col0 + wc * 128;
        __syncthreads();
#pragma unroll
        for (int j = 0; j < 8; ++j) {
            int n = j * 16 + (lane >> 2);
            int mo = (lane & 3) * 8;
            f16x8 val = *(const f16x8*)(reg + n * 64 + mo * 2);
            *(f16x8*)(vt + (size_t)(b * 512 + u_base + n) * 2048 + s_base + mo) = val;
        }
    }
}

// Score GEMM (R10 form), 128x128 tiles, batch-pinned, swizzled,
// __syncthreads-fenced.
__global__ __launch_bounds__(256) void score_kernel(
    const _Float16* __restrict__ qh, const _Float16* __restrict__ kh,
    float* __restrict__ S) {
    __shared__ __align__(16) char smem[32768];
    const int b = blockIdx.x;
    const int z = b & 7, r = b >> 3;
    const int by = r >> 4, bx = r & 15;
    const int tid = threadIdx.x;
    const int wave = tid >> 6, lane = tid & 63;
    const int quad = lane >> 4, m16 = lane & 15;
    const int wr = wave >> 1, wc = wave & 1;
    const int row0 = z * 1024 + by * 128;
    const int col0 = bx * 128;

    const int scol = ((lane & 3) ^ ((lane >> 3) & 3)) * 8;
    const int srow = wave * 32 + (lane >> 2);
    const _Float16* agp = qh + (size_t)(row0 + srow) * 512 + scol;
    const _Float16* bgp = kh + (size_t)(z * 2048 + col0 + srow) * 512 + scol;
    const int ldsAoff = wave * 2048;
    const int ldsBoff = 8192 + wave * 2048;

    f32x4 acc[4][4];
#pragma unroll
    for (int mt = 0; mt < 4; ++mt)
#pragma unroll
        for (int nt = 0; nt < 4; ++nt) acc[mt][nt] = (f32x4){0.f, 0.f, 0.f, 0.f};

    auto stage = [&](int i, int buf) {
        char* base = smem + buf * 16384;
        const int k0 = i * 32;
#pragma unroll
        for (int j = 0; j < 2; ++j) {
            glds16(agp + k0 + j * 16 * 512, base + ldsAoff + j * 1024);
            glds16(bgp + k0 + j * 16 * 512, base + ldsBoff + j * 1024);
        }
    };

    const int csw = (quad ^ ((lane >> 1) & 3)) * 16;

    stage(0, 0);
    for (int i = 0; i < 16; ++i) {
        __syncthreads();
        if (i + 1 < 16) stage(i + 1, (i + 1) & 1);
        const char* bb = smem + (i & 1) * 16384;
        const char* pa = bb + (wr * 64 + m16) * 64 + csw;
        const char* pb = bb + 8192 + (wc * 64 + m16) * 64 + csw;
        f16x8 af[4];
#pragma unroll
        for (int mt = 0; mt < 4; ++mt) af[mt] = *(const f16x8*)(pa + mt * 1024);
#pragma unroll
        for (int nt = 0; nt < 4; ++nt) {
            f16x8 bf = *(const f16x8*)(pb + nt * 1024);
#pragma unroll
            for (int mt = 0; mt < 4; ++mt) acc[mt][nt] = MFMA16(af[mt], bf, acc[mt][nt]);
        }
    }
#pragma unroll
    for (int mt = 0; mt < 4; ++mt)
#pragma unroll
        for (int nt = 0; nt < 4; ++nt)
#pragma unroll
            for (int rr = 0; rr < 4; ++rr) {
                int row = row0 + wr * 64 + mt * 16 + quad * 4 + rr;
                int col = col0 + wc * 64 + nt * 16 + m16;
                S[(size_t)row * 2048 + col] = acc[mt][nt][rr];
            }
}

// Row softmax over 2048 cols, fp32 in -> fp16 out (normalized). One block/row.
__global__ __launch_bounds__(256) void softmax_kernel(const float* __restrict__ S,
                                                      _Float16* __restrict__ P) {
    const int row = blockIdx.x;
    const int tid = threadIdx.x;
    const int wave = tid >> 6, lane = tid & 63;
    __shared__ float red[8];

    const float* sp = S + (size_t)row * 2048 + tid * 8;
    float4 x0 = *(const float4*)sp;
    float4 x1 = *(const float4*)(sp + 4);
    float v[8] = {x0.x, x0.y, x0.z, x0.w, x1.x, x1.y, x1.z, x1.w};

    float mx = v[0];
#pragma unroll
    for (int i = 1; i < 8; ++i) mx = fmaxf(mx, v[i]);
#pragma unroll
    for (int off = 32; off > 0; off >>= 1) mx = fmaxf(mx, __shfl_down(mx, off));
    if (lane == 0) red[wave] = mx;
    __syncthreads();
    if (tid == 0) red[4] = fmaxf(fmaxf(red[0], red[1]), fmaxf(red[2], red[3]));
    __syncthreads();
    mx = red[4];

    float e[8];
    float sum = 0.f;
#pragma unroll
    for (int i = 0; i < 8; ++i) {
        e[i] = exp2f((v[i] - mx) * L2E);
        sum += e[i];
    }
#pragma unroll
    for (int off = 32; off > 0; off >>= 1) sum += __shfl_down(sum, off);
    if (lane == 0) red[wave] = sum;
    __syncthreads();
    if (tid == 0) red[5] = red[0] + red[1] + red[2] + red[3];
    __syncthreads();
    float inv = 1.0f / red[5];

    f16x8 ov;
#pragma unroll
    for (int i = 0; i < 8; ++i) ov[i] = (_Float16)(e[i] * inv);
    *(f16x8*)(P + (size_t)row * 2048 + tid * 8) = ov;
}

// PV GEMM (R16): 64q x 256u tiles, __syncthreads-fenced dbuf -- verbatim
// R10-proj K-loop with stride 2048, 64 K-iters, 5 glds/wave/step. Grid 256:
// z = b&7 (XCD pin, vt[z] 2MB L2-resident), r = b>>3 in [0,32): by = r>>1
// (q-tile of 64), bx = r&1 (u-slab of 256; both slabs same XCD -> P rows
// L2-shared).
__global__ __launch_bounds__(256) void pv_kernel(
    const _Float16* __restrict__ P, const _Float16* __restrict__ vt,
    float* __restrict__ out) {
    __shared__ __align__(16) char smem[40960];
    const int b = blockIdx.x;
    const int z = b & 7, r = b >> 3;
    const int by = r >> 1, bx = r & 1;
    const int tid = threadIdx.x;
    const int wave = tid >> 6, lane = tid & 63;
    const int quad = lane >> 4, m16 = lane & 15;
    const int wr = wave >> 1, wc = wave & 1;
    const int row0 = z * 1024 + by * 64;
    const int col0 = bx * 256;

    const int scol = ((lane & 3) ^ ((lane >> 3) & 3)) * 8;
    const int srowA = wave * 16 + (lane >> 2);
    const int srowB = wave * 64 + (lane >> 2);
    const _Float16* agp = P + (size_t)(row0 + srowA) * 2048 + scol;
    const _Float16* bgp = vt + (size_t)(z * 512 + col0 + srowB) * 2048 + scol;
    const int ldsAoff = wave * 1024;
    const int ldsBoff = 4096 + wave * 4096;

    f32x4 acc[2][8];
#pragma unroll
    for (int mt = 0; mt < 2; ++mt)
#pragma unroll
        for (int nt = 0; nt < 8; ++nt) acc[mt][nt] = (f32x4){0.f, 0.f, 0.f, 0.f};

    auto stage = [&](int i, int buf) {
        char* base = smem + buf * 20480;
        const int k0 = i * 32;
        glds16(agp + k0, base + ldsAoff);
#pragma unroll
        for (int j = 0; j < 4; ++j)
            glds16(bgp + k0 + j * 16 * 2048, base + ldsBoff + j * 1024);
    };

    const int csw = (quad ^ ((lane >> 1) & 3)) * 16;

    stage(0, 0);
    for (int i = 0; i < 64; ++i) {
        __syncthreads();
        if (i + 1 < 64) stage(i + 1, (i + 1) & 1);
        const char* bb = smem + (i & 1) * 20480;
        const char* pa = bb + (wr * 32 + m16) * 64 + csw;
        const char* pb = bb + 4096 + (wc * 128 + m16) * 64 + csw;
        f16x8 af[2];
#pragma unroll
        for (int mt = 0; mt < 2; ++mt) af[mt] = *(const f16x8*)(pa + mt * 1024);
#pragma unroll
        for (int nt = 0; nt < 8; ++nt) {
            f16x8 bf = *(const f16x8*)(pb + nt * 1024);
#pragma unroll
            for (int mt = 0; mt < 2; ++mt) acc[mt][nt] = MFMA16(af[mt], bf, acc[mt][nt]);
        }
    }

#pragma unroll
    for (int mt = 0; mt < 2; ++mt)
#pragma unroll
        for (int nt = 0; nt < 8; ++nt)
#pragma unroll
            for (int rr = 0; rr < 4; ++rr) {
                int row = row0 + wr * 32 + mt * 16 + quad * 4 + rr;
                int col = col0 + wc * 128 + nt * 16 + m16;
                out[(size_t)row * 512 + col] = acc[mt][nt][rr];
            }
}

extern "C" void kernel_launch(void* const* d_in, const int* in_sizes, int n_in,
                              void* d_out, int out_size, void* d_ws, size_t ws_size,
                              hipStream_t stream) {
    const float* enc = (const float*)d_in[0];  // [8,2048,512]
    const float* dec = (const float*)d_in[1];  // [8,1024,512]
    const float* Wq = (const float*)d_in[2];   // [512,512]
    const float* Wk = (const float*)d_in[3];
    const float* Wv = (const float*)d_in[4];
    float* out = (float*)d_out;                // [8,1024,512] fp32

    char* ws = (char*)d_ws;
    _Float16* qh = (_Float16*)(ws);
    _Float16* kh = (_Float16*)(ws + ((size_t)8 << 20));
    _Float16* P = (_Float16*)(ws);                          // aliases qh/kh after score
    _Float16* vt = (_Float16*)(ws + ((size_t)32 << 20));
    float* S = (float*)(ws + ((size_t)48 << 20));
    _Float16* dech = (_Float16*)(ws + ((size_t)48 << 20));  // dead before S written
    _Float16* wts = (_Float16*)(ws + ((size_t)56 << 20));   // dead before S written
    _Float16* ench = (_Float16*)(ws + ((size_t)112 << 20)); // dead after proj

    dim3 blk(256);
    prep_kernel<<<6336, blk, 0, stream>>>(enc, dec, Wq, Wk, Wv, ench, dech, wts);
    proj_kernel<<<1280, blk, 0, stream>>>(dech, ench, wts, qh, kh, vt);
    score_kernel<<<1024, blk, 0, stream>>>(qh, kh, S);
    softmax_kernel<<<8192, blk, 0, stream>>>(S, P);
    pv_kernel<<<256, blk, 0, stream>>>(P, vt, out);
}

// Round 8
// 201.582 us; speedup vs baseline: 1.1405x; 1.0308x over previous
//
#include <hip/hip_runtime.h>
#include <hip/hip_bf16.h>

// Cross-attention B=8, S_ENC=2048, S_DEC=1024, D=512, U=512.
// R17: (a) pv reverted to R10 proven form (64x128, 512 blocks = 2 blocks/CU;
// R16's 64x256 halved grid to 1 block/CU and lost the inter-block overlap
// that hides the syncthreads drain -> -10us regression). (b) enc/dec fp32->
// fp16 conversion folded into proj's A-staging (reg-stage: 2x float4 load ->
// cvt -> ds_write_b128 at base+lane*16, bit-identical LDS layout to glds;
// B-path keeps glds16). prep shrinks to W-transpose only (192 blocks).
// Saves ~96MB read + 48MB write of prep HBM traffic + a launch.
// All kernels remain __syncthreads-fenced (the only structure that has
// passed every time).
//
// ws: qh [0,8M) | kh [8M,24M) | P [0,32M) (after score) | vt [32M,48M) |
//     S [48M,112M) fp32 | wts @56M (dead pre-S)

typedef __attribute__((ext_vector_type(8))) _Float16 f16x8;
typedef __attribute__((ext_vector_type(4))) _Float16 f16x4;
typedef __attribute__((ext_vector_type(4))) float f32x4;

#define MFMA16(a, b, c) __builtin_amdgcn_mfma_f32_16x16x32_f16(a, b, c, 0, 0, 0)
#define L2E 1.44269504088896f

__device__ __forceinline__ void glds16(const void* g, void* l) {
    __builtin_amdgcn_global_load_lds(
        (const __attribute__((address_space(1))) void*)g,
        (__attribute__((address_space(3))) void*)l, 16, 0, 0);
}

// prep: W transpose only. 192 blocks: zw = bid>>6 selects Wq/Wk/Wv.
__global__ __launch_bounds__(256) void prep_kernel(
    const float* __restrict__ Wq, const float* __restrict__ Wk,
    const float* __restrict__ Wv, _Float16* __restrict__ planes) {
    const int t = blockIdx.x;
    const int zw = t >> 6, r = t & 63;
    const int u0 = (r & 7) * 64, d0 = (r >> 3) * 64;
    const float* W = zw == 0 ? Wq : (zw == 1 ? Wk : Wv);
    _Float16* ot = planes + (size_t)zw * 262144;
    __shared__ float T[64][65];
    const int tr = threadIdx.x >> 4, tc = (threadIdx.x & 15) * 4;
#pragma unroll
    for (int j = 0; j < 4; ++j) {
        float4 vv = *(const float4*)(W + (size_t)(d0 + tr + j * 16) * 512 + u0 + tc);
        T[tr + j * 16][tc + 0] = vv.x;
        T[tr + j * 16][tc + 1] = vv.y;
        T[tr + j * 16][tc + 2] = vv.z;
        T[tr + j * 16][tc + 3] = vv.w;
    }
    __syncthreads();
#pragma unroll
    for (int j = 0; j < 4; ++j) {
        int ul = tr + j * 16;
        f16x4 h;
#pragma unroll
        for (int i = 0; i < 4; ++i) h[i] = (_Float16)T[tc + i][ul];
        *(f16x4*)(ot + (size_t)(u0 + ul) * 512 + d0 + tc) = h;
    }
}

// Unified projections (R17): 64x256 tiles, K=512, dbuf LDS, swizzled,
// __syncthreads-fenced. A-path reads fp32 enc/dec DIRECTLY and converts in
// registers (2x float4 -> 8 cvt -> ds_write_b128 at base+lane*16 == the
// layout glds16 produced, so the swizzled read is unchanged). B-path glds16.
__global__ __launch_bounds__(256) void proj_kernel(
    const float* __restrict__ dec, const float* __restrict__ enc,
    const _Float16* __restrict__ wts, _Float16* __restrict__ qh,
    _Float16* __restrict__ kh, _Float16* __restrict__ vt) {
    __shared__ __align__(16) char smem[40960];
    const int bid = blockIdx.x;
    int seg, bx, by;
    if (bid < 256) { seg = 0; by = bid & 127; bx = bid >> 7; }
    else if (bid < 768) { int t = bid - 256; seg = 1; by = t & 255; bx = t >> 8; }
    else { int t = bid - 768; seg = 2; by = t & 255; bx = t >> 8; }
    const float* A = seg == 0 ? dec : enc;
    const _Float16* Bp = wts + (size_t)seg * 262144;

    const int tid = threadIdx.x;
    const int wave = tid >> 6, lane = tid & 63;
    const int quad = lane >> 4, m16 = lane & 15;
    const int wr = wave >> 1, wc = wave & 1;
    const int row0 = by * 64, col0 = bx * 256;

    // source pre-swizzle: lane L feeds LDS slot (r=L>>2, c=L&3); slot c must
    // hold global chunk c ^ ((r>>1)&3) -> read chunk (L&3)^((L>>3)&3).
    const int scol = ((lane & 3) ^ ((lane >> 3) & 3)) * 8;
    const int srowA = wave * 16 + (lane >> 2);
    const int srowB = wave * 64 + (lane >> 2);
    const float* agp = A + (size_t)(row0 + srowA) * 512 + scol;  // fp32
    const _Float16* bgp = Bp + (size_t)(col0 + srowB) * 512 + scol;
    const int ldsAoff = wave * 1024;
    const int ldsBoff = 4096 + wave * 4096;

    f32x4 acc[2][8];
#pragma unroll
    for (int mt = 0; mt < 2; ++mt)
#pragma unroll
        for (int nt = 0; nt < 8; ++nt) acc[mt][nt] = (f32x4){0.f, 0.f, 0.f, 0.f};

    auto stage = [&](int i, int buf) {
        char* base = smem + buf * 20480;
        const int k0 = i * 32;
        // B: async glds16 x4
#pragma unroll
        for (int j = 0; j < 4; ++j)
            glds16(bgp + k0 + j * 16 * 512, base + ldsBoff + j * 1024);
        // A: fp32 load -> cvt fp16 -> ds_write (same layout glds would make)
        float4 a0 = *(const float4*)(agp + k0);
        float4 a1 = *(const float4*)(agp + k0 + 4);
        f16x8 h;
        h[0] = (_Float16)a0.x; h[1] = (_Float16)a0.y;
        h[2] = (_Float16)a0.z; h[3] = (_Float16)a0.w;
        h[4] = (_Float16)a1.x; h[5] = (_Float16)a1.y;
        h[6] = (_Float16)a1.z; h[7] = (_Float16)a1.w;
        *(f16x8*)(base + ldsAoff + lane * 16) = h;
    };

    // swizzled read slot: chunk quad of row (…+m16) sits at slot quad^((m16>>1)&3)
    const int csw = (quad ^ ((lane >> 1) & 3)) * 16;

    stage(0, 0);
    for (int i = 0; i < 16; ++i) {
        __syncthreads();
        if (i + 1 < 16) stage(i + 1, (i + 1) & 1);
        const char* bb = smem + (i & 1) * 20480;
        const char* pa = bb + (wr * 32 + m16) * 64 + csw;
        const char* pb = bb + 4096 + (wc * 128 + m16) * 64 + csw;
        f16x8 af[2];
#pragma unroll
        for (int mt = 0; mt < 2; ++mt) af[mt] = *(const f16x8*)(pa + mt * 1024);
#pragma unroll
        for (int nt = 0; nt < 8; ++nt) {
            f16x8 bf = *(const f16x8*)(pb + nt * 1024);
#pragma unroll
            for (int mt = 0; mt < 2; ++mt) acc[mt][nt] = MFMA16(af[mt], bf, acc[mt][nt]);
        }
    }

    if (seg < 2) {
        _Float16* o = seg == 0 ? qh : kh;
#pragma unroll
        for (int mt = 0; mt < 2; ++mt)
#pragma unroll
            for (int nt = 0; nt < 8; ++nt)
#pragma unroll
                for (int rr = 0; rr < 4; ++rr) {
                    int row = row0 + wr * 32 + mt * 16 + quad * 4 + rr;
                    int col = col0 + wc * 128 + nt * 16 + m16;
                    o[(size_t)row * 512 + col] = (_Float16)acc[mt][nt][rr];
                }
    } else {
        __syncthreads();
        char* reg = smem + wave * 8192;  // [128 n][32 m] fp16 per-wave scratch
#pragma unroll
        for (int nt = 0; nt < 8; ++nt)
#pragma unroll
            for (int mt = 0; mt < 2; ++mt) {
                f16x4 pk;
#pragma unroll
                for (int rr = 0; rr < 4; ++rr) pk[rr] = (_Float16)acc[mt][nt][rr];
                *(f16x4*)(reg + (nt * 16 + m16) * 64 + (mt * 16 + quad * 4) * 2) = pk;
            }
        const int b = row0 >> 11;
        const int s_base = (row0 & 2047) + wr * 32;
        const int u_base = col0 + wc * 128;
        __syncthreads();
#pragma unroll
        for (int j = 0; j < 8; ++j) {
            int n = j * 16 + (lane >> 2);
            int mo = (lane & 3) * 8;
            f16x8 val = *(const f16x8*)(reg + n * 64 + mo * 2);
            *(f16x8*)(vt + (size_t)(b * 512 + u_base + n) * 2048 + s_base + mo) = val;
        }
    }
}

// Score GEMM (R10 form), 128x128 tiles, batch-pinned, swizzled,
// __syncthreads-fenced.
__global__ __launch_bounds__(256) void score_kernel(
    const _Float16* __restrict__ qh, const _Float16* __restrict__ kh,
    float* __restrict__ S) {
    __shared__ __align__(16) char smem[32768];
    const int b = blockIdx.x;
    const int z = b & 7, r = b >> 3;
    const int by = r >> 4, bx = r & 15;
    const int tid = threadIdx.x;
    const int wave = tid >> 6, lane = tid & 63;
    const int quad = lane >> 4, m16 = lane & 15;
    const int wr = wave >> 1, wc = wave & 1;
    const int row0 = z * 1024 + by * 128;
    const int col0 = bx * 128;

    const int scol = ((lane & 3) ^ ((lane >> 3) & 3)) * 8;
    const int srow = wave * 32 + (lane >> 2);
    const _Float16* agp = qh + (size_t)(row0 + srow) * 512 + scol;
    const _Float16* bgp = kh + (size_t)(z * 2048 + col0 + srow) * 512 + scol;
    const int ldsAoff = wave * 2048;
    const int ldsBoff = 8192 + wave * 2048;

    f32x4 acc[4][4];
#pragma unroll
    for (int mt = 0; mt < 4; ++mt)
#pragma unroll
        for (int nt = 0; nt < 4; ++nt) acc[mt][nt] = (f32x4){0.f, 0.f, 0.f, 0.f};

    auto stage = [&](int i, int buf) {
        char* base = smem + buf * 16384;
        const int k0 = i * 32;
#pragma unroll
        for (int j = 0; j < 2; ++j) {
            glds16(agp + k0 + j * 16 * 512, base + ldsAoff + j * 1024);
            glds16(bgp + k0 + j * 16 * 512, base + ldsBoff + j * 1024);
        }
    };

    const int csw = (quad ^ ((lane >> 1) & 3)) * 16;

    stage(0, 0);
    for (int i = 0; i < 16; ++i) {
        __syncthreads();
        if (i + 1 < 16) stage(i + 1, (i + 1) & 1);
        const char* bb = smem + (i & 1) * 16384;
        const char* pa = bb + (wr * 64 + m16) * 64 + csw;
        const char* pb = bb + 8192 + (wc * 64 + m16) * 64 + csw;
        f16x8 af[4];
#pragma unroll
        for (int mt = 0; mt < 4; ++mt) af[mt] = *(const f16x8*)(pa + mt * 1024);
#pragma unroll
        for (int nt = 0; nt < 4; ++nt) {
            f16x8 bf = *(const f16x8*)(pb + nt * 1024);
#pragma unroll
            for (int mt = 0; mt < 4; ++mt) acc[mt][nt] = MFMA16(af[mt], bf, acc[mt][nt]);
        }
    }
#pragma unroll
    for (int mt = 0; mt < 4; ++mt)
#pragma unroll
        for (int nt = 0; nt < 4; ++nt)
#pragma unroll
            for (int rr = 0; rr < 4; ++rr) {
                int row = row0 + wr * 64 + mt * 16 + quad * 4 + rr;
                int col = col0 + wc * 64 + nt * 16 + m16;
                S[(size_t)row * 2048 + col] = acc[mt][nt][rr];
            }
}

// Row softmax over 2048 cols, fp32 in -> fp16 out (normalized). One block/row.
__global__ __launch_bounds__(256) void softmax_kernel(const float* __restrict__ S,
                                                      _Float16* __restrict__ P) {
    const int row = blockIdx.x;
    const int tid = threadIdx.x;
    const int wave = tid >> 6, lane = tid & 63;
    __shared__ float red[8];

    const float* sp = S + (size_t)row * 2048 + tid * 8;
    float4 x0 = *(const float4*)sp;
    float4 x1 = *(const float4*)(sp + 4);
    float v[8] = {x0.x, x0.y, x0.z, x0.w, x1.x, x1.y, x1.z, x1.w};

    float mx = v[0];
#pragma unroll
    for (int i = 1; i < 8; ++i) mx = fmaxf(mx, v[i]);
#pragma unroll
    for (int off = 32; off > 0; off >>= 1) mx = fmaxf(mx, __shfl_down(mx, off));
    if (lane == 0) red[wave] = mx;
    __syncthreads();
    if (tid == 0) red[4] = fmaxf(fmaxf(red[0], red[1]), fmaxf(red[2], red[3]));
    __syncthreads();
    mx = red[4];

    float e[8];
    float sum = 0.f;
#pragma unroll
    for (int i = 0; i < 8; ++i) {
        e[i] = exp2f((v[i] - mx) * L2E);
        sum += e[i];
    }
#pragma unroll
    for (int off = 32; off > 0; off >>= 1) sum += __shfl_down(sum, off);
    if (lane == 0) red[wave] = sum;
    __syncthreads();
    if (tid == 0) red[5] = red[0] + red[1] + red[2] + red[3];
    __syncthreads();
    float inv = 1.0f / red[5];

    f16x8 ov;
#pragma unroll
    for (int i = 0; i < 8; ++i) ov[i] = (_Float16)(e[i] * inv);
    *(f16x8*)(P + (size_t)row * 2048 + tid * 8) = ov;
}

// PV GEMM (R10 proven form): 64q x 128u tiles, 512 blocks (2 blocks/CU),
// batch-pinned (z = b&7, vt[z] L2-resident), swizzled, __syncthreads-fenced.
__global__ __launch_bounds__(256) void pv_kernel(
    const _Float16* __restrict__ P, const _Float16* __restrict__ vt,
    float* __restrict__ out) {
    __shared__ __align__(16) char smem[24576];
    const int b = blockIdx.x;
    const int z = b & 7, r = b >> 3;
    const int by = r >> 2, bx = r & 3;
    const int tid = threadIdx.x;
    const int wave = tid >> 6, lane = tid & 63;
    const int quad = lane >> 4, m16 = lane & 15;
    const int wr = wave >> 1, wc = wave & 1;
    const int row0 = z * 1024 + by * 64;
    const int col0 = bx * 128;

    const int scol = ((lane & 3) ^ ((lane >> 3) & 3)) * 8;
    const int srowA = wave * 16 + (lane >> 2);
    const int srowB = wave * 32 + (lane >> 2);
    const _Float16* agp = P + (size_t)(row0 + srowA) * 2048 + scol;
    const _Float16* bgp = vt + (size_t)(z * 512 + col0 + srowB) * 2048 + scol;
    const int ldsAoff = wave * 1024;
    const int ldsBoff = 4096 + wave * 2048;

    f32x4 acc[2][4];
#pragma unroll
    for (int mt = 0; mt < 2; ++mt)
#pragma unroll
        for (int nt = 0; nt < 4; ++nt) acc[mt][nt] = (f32x4){0.f, 0.f, 0.f, 0.f};

    auto stage = [&](int i, int buf) {
        char* base = smem + buf * 12288;
        const int k0 = i * 32;
        glds16(agp + k0, base + ldsAoff);
#pragma unroll
        for (int j = 0; j < 2; ++j)
            glds16(bgp + k0 + j * 16 * 2048, base + ldsBoff + j * 1024);
    };

    const int csw = (quad ^ ((lane >> 1) & 3)) * 16;

    stage(0, 0);
    for (int i = 0; i < 64; ++i) {
        __syncthreads();
        if (i + 1 < 64) stage(i + 1, (i + 1) & 1);
        const char* bb = smem + (i & 1) * 12288;
        const char* pa = bb + (wr * 32 + m16) * 64 + csw;
        const char* pb = bb + 4096 + (wc * 64 + m16) * 64 + csw;
        f16x8 af[2];
#pragma unroll
        for (int mt = 0; mt < 2; ++mt) af[mt] = *(const f16x8*)(pa + mt * 1024);
#pragma unroll
        for (int nt = 0; nt < 4; ++nt) {
            f16x8 bf = *(const f16x8*)(pb + nt * 1024);
#pragma unroll
            for (int mt = 0; mt < 2; ++mt) acc[mt][nt] = MFMA16(af[mt], bf, acc[mt][nt]);
        }
    }

#pragma unroll
    for (int mt = 0; mt < 2; ++mt)
#pragma unroll
        for (int nt = 0; nt < 4; ++nt)
#pragma unroll
            for (int rr = 0; rr < 4; ++rr) {
                int row = row0 + wr * 32 + mt * 16 + quad * 4 + rr;
                int col = col0 + wc * 64 + nt * 16 + m16;
                out[(size_t)row * 512 + col] = acc[mt][nt][rr];
            }
}

extern "C" void kernel_launch(void* const* d_in, const int* in_sizes, int n_in,
                              void* d_out, int out_size, void* d_ws, size_t ws_size,
                              hipStream_t stream) {
    const float* enc = (const float*)d_in[0];  // [8,2048,512]
    const float* dec = (const float*)d_in[1];  // [8,1024,512]
    const float* Wq = (const float*)d_in[2];   // [512,512]
    const float* Wk = (const float*)d_in[3];
    const float* Wv = (const float*)d_in[4];
    float* out = (float*)d_out;                // [8,1024,512] fp32

    char* ws = (char*)d_ws;
    _Float16* qh = (_Float16*)(ws);
    _Float16* kh = (_Float16*)(ws + ((size_t)8 << 20));
    _Float16* P = (_Float16*)(ws);                          // aliases qh/kh after score
    _Float16* vt = (_Float16*)(ws + ((size_t)32 << 20));
    float* S = (float*)(ws + ((size_t)48 << 20));
    _Float16* wts = (_Float16*)(ws + ((size_t)56 << 20));   // dead before S written

    dim3 blk(256);
    prep_kernel<<<192, blk, 0, stream>>>(Wq, Wk, Wv, wts);
    proj_kernel<<<1280, blk, 0, stream>>>(dec, enc, wts, qh, kh, vt);
    score_kernel<<<1024, blk, 0, stream>>>(qh, kh, S);
    softmax_kernel<<<8192, blk, 0, stream>>>(S, P);
    pv_kernel<<<512, blk, 0, stream>>>(P, vt, out);
}

// Round 9
// 200.097 us; speedup vs baseline: 1.1490x; 1.0074x over previous
//
#include <hip/hip_runtime.h>
#include <hip/hip_bf16.h>

// Cross-attention B=8, S_ENC=2048, S_DEC=1024, D=512, U=512.
// R18: T14 async-STAGE split on proj's A-path. R17 fused the fp32->fp16 cvt
// into proj but placed load->cvt->ds_write BEFORE the MFMA phase: the
// compiler's waitcnt before ds_write exposed full HBM latency per K-step
// (proj 41->52us, MfmaUtil 20->15.4%). Now: issue the two float4 loads right
// after the barrier, run the MFMA phase, then cvt+ds_write at the END of the
// body (write still lands in the barrier-protected window for buf(i+1)).
// B-path keeps fire-and-forget glds16. prep/score/softmax/pv = R17 (proven).
//
// ws: qh [0,8M) | kh [8M,24M) | P [0,32M) (after score) | vt [32M,48M) |
//     S [48M,112M) fp32 | wts @56M (dead pre-S)

typedef __attribute__((ext_vector_type(8))) _Float16 f16x8;
typedef __attribute__((ext_vector_type(4))) _Float16 f16x4;
typedef __attribute__((ext_vector_type(4))) float f32x4;

#define MFMA16(a, b, c) __builtin_amdgcn_mfma_f32_16x16x32_f16(a, b, c, 0, 0, 0)
#define L2E 1.44269504088896f

__device__ __forceinline__ void glds16(const void* g, void* l) {
    __builtin_amdgcn_global_load_lds(
        (const __attribute__((address_space(1))) void*)g,
        (__attribute__((address_space(3))) void*)l, 16, 0, 0);
}

// prep: W transpose only. 192 blocks: zw = bid>>6 selects Wq/Wk/Wv.
__global__ __launch_bounds__(256) void prep_kernel(
    const float* __restrict__ Wq, const float* __restrict__ Wk,
    const float* __restrict__ Wv, _Float16* __restrict__ planes) {
    const int t = blockIdx.x;
    const int zw = t >> 6, r = t & 63;
    const int u0 = (r & 7) * 64, d0 = (r >> 3) * 64;
    const float* W = zw == 0 ? Wq : (zw == 1 ? Wk : Wv);
    _Float16* ot = planes + (size_t)zw * 262144;
    __shared__ float T[64][65];
    const int tr = threadIdx.x >> 4, tc = (threadIdx.x & 15) * 4;
#pragma unroll
    for (int j = 0; j < 4; ++j) {
        float4 vv = *(const float4*)(W + (size_t)(d0 + tr + j * 16) * 512 + u0 + tc);
        T[tr + j * 16][tc + 0] = vv.x;
        T[tr + j * 16][tc + 1] = vv.y;
        T[tr + j * 16][tc + 2] = vv.z;
        T[tr + j * 16][tc + 3] = vv.w;
    }
    __syncthreads();
#pragma unroll
    for (int j = 0; j < 4; ++j) {
        int ul = tr + j * 16;
        f16x4 h;
#pragma unroll
        for (int i = 0; i < 4; ++i) h[i] = (_Float16)T[tc + i][ul];
        *(f16x4*)(ot + (size_t)(u0 + ul) * 512 + d0 + tc) = h;
    }
}

// Unified projections (R18): 64x256 tiles, K=512, dbuf LDS, swizzled,
// __syncthreads-fenced. A-path: fp32 loads issued early (post-barrier),
// cvt+ds_write late (post-MFMA) -- T14 split. B-path glds16.
__global__ __launch_bounds__(256) void proj_kernel(
    const float* __restrict__ dec, const float* __restrict__ enc,
    const _Float16* __restrict__ wts, _Float16* __restrict__ qh,
    _Float16* __restrict__ kh, _Float16* __restrict__ vt) {
    __shared__ __align__(16) char smem[40960];
    const int bid = blockIdx.x;
    int seg, bx, by;
    if (bid < 256) { seg = 0; by = bid & 127; bx = bid >> 7; }
    else if (bid < 768) { int t = bid - 256; seg = 1; by = t & 255; bx = t >> 8; }
    else { int t = bid - 768; seg = 2; by = t & 255; bx = t >> 8; }
    const float* A = seg == 0 ? dec : enc;
    const _Float16* Bp = wts + (size_t)seg * 262144;

    const int tid = threadIdx.x;
    const int wave = tid >> 6, lane = tid & 63;
    const int quad = lane >> 4, m16 = lane & 15;
    const int wr = wave >> 1, wc = wave & 1;
    const int row0 = by * 64, col0 = bx * 256;

    // source pre-swizzle: lane L feeds LDS slot (r=L>>2, c=L&3); slot c must
    // hold global chunk c ^ ((r>>1)&3) -> read chunk (L&3)^((L>>3)&3).
    const int scol = ((lane & 3) ^ ((lane >> 3) & 3)) * 8;
    const int srowA = wave * 16 + (lane >> 2);
    const int srowB = wave * 64 + (lane >> 2);
    const float* agp = A + (size_t)(row0 + srowA) * 512 + scol;  // fp32
    const _Float16* bgp = Bp + (size_t)(col0 + srowB) * 512 + scol;
    const int ldsAoff = wave * 1024;
    const int ldsBoff = 4096 + wave * 4096;

    f32x4 acc[2][8];
#pragma unroll
    for (int mt = 0; mt < 2; ++mt)
#pragma unroll
        for (int nt = 0; nt < 8; ++nt) acc[mt][nt] = (f32x4){0.f, 0.f, 0.f, 0.f};

    auto stageB = [&](int i, int buf) {
        char* base = smem + buf * 20480;
        const int k0 = i * 32;
#pragma unroll
        for (int j = 0; j < 4; ++j)
            glds16(bgp + k0 + j * 16 * 512, base + ldsBoff + j * 1024);
    };
    auto writeA = [&](int buf, float4 a0, float4 a1) {
        char* base = smem + buf * 20480;
        f16x8 h;
        h[0] = (_Float16)a0.x; h[1] = (_Float16)a0.y;
        h[2] = (_Float16)a0.z; h[3] = (_Float16)a0.w;
        h[4] = (_Float16)a1.x; h[5] = (_Float16)a1.y;
        h[6] = (_Float16)a1.z; h[7] = (_Float16)a1.w;
        *(f16x8*)(base + ldsAoff + lane * 16) = h;
    };

    // swizzled read slot: chunk quad of row (…+m16) sits at slot quad^((m16>>1)&3)
    const int csw = (quad ^ ((lane >> 1) & 3)) * 16;

    // prologue: full stage of tile 0
    {
        stageB(0, 0);
        float4 a0 = *(const float4*)(agp);
        float4 a1 = *(const float4*)(agp + 4);
        writeA(0, a0, a1);
    }
    for (int i = 0; i < 16; ++i) {
        __syncthreads();
        float4 na0, na1;
        if (i + 1 < 16) {
            stageB(i + 1, (i + 1) & 1);                 // async B
            na0 = *(const float4*)(agp + (i + 1) * 32); // issue A loads early
            na1 = *(const float4*)(agp + (i + 1) * 32 + 4);
        }
        const char* bb = smem + (i & 1) * 20480;
        const char* pa = bb + (wr * 32 + m16) * 64 + csw;
        const char* pb = bb + 4096 + (wc * 128 + m16) * 64 + csw;
        f16x8 af[2];
#pragma unroll
        for (int mt = 0; mt < 2; ++mt) af[mt] = *(const f16x8*)(pa + mt * 1024);
#pragma unroll
        for (int nt = 0; nt < 8; ++nt) {
            f16x8 bf = *(const f16x8*)(pb + nt * 1024);
#pragma unroll
            for (int mt = 0; mt < 2; ++mt) acc[mt][nt] = MFMA16(af[mt], bf, acc[mt][nt]);
        }
        if (i + 1 < 16) writeA((i + 1) & 1, na0, na1);  // cvt+write late
    }

    if (seg < 2) {
        _Float16* o = seg == 0 ? qh : kh;
#pragma unroll
        for (int mt = 0; mt < 2; ++mt)
#pragma unroll
            for (int nt = 0; nt < 8; ++nt)
#pragma unroll
                for (int rr = 0; rr < 4; ++rr) {
                    int row = row0 + wr * 32 + mt * 16 + quad * 4 + rr;
                    int col = col0 + wc * 128 + nt * 16 + m16;
                    o[(size_t)row * 512 + col] = (_Float16)acc[mt][nt][rr];
                }
    } else {
        __syncthreads();
        char* reg = smem + wave * 8192;  // [128 n][32 m] fp16 per-wave scratch
#pragma unroll
        for (int nt = 0; nt < 8; ++nt)
#pragma unroll
            for (int mt = 0; mt < 2; ++mt) {
                f16x4 pk;
#pragma unroll
                for (int rr = 0; rr < 4; ++rr) pk[rr] = (_Float16)acc[mt][nt][rr];
                *(f16x4*)(reg + (nt * 16 + m16) * 64 + (mt * 16 + quad * 4) * 2) = pk;
            }
        const int b = row0 >> 11;
        const int s_base = (row0 & 2047) + wr * 32;
        const int u_base = col0 + wc * 128;
        __syncthreads();
#pragma unroll
        for (int j = 0; j < 8; ++j) {
            int n = j * 16 + (lane >> 2);
            int mo = (lane & 3) * 8;
            f16x8 val = *(const f16x8*)(reg + n * 64 + mo * 2);
            *(f16x8*)(vt + (size_t)(b * 512 + u_base + n) * 2048 + s_base + mo) = val;
        }
    }
}

// Score GEMM (R10 form), 128x128 tiles, batch-pinned, swizzled,
// __syncthreads-fenced.
__global__ __launch_bounds__(256) void score_kernel(
    const _Float16* __restrict__ qh, const _Float16* __restrict__ kh,
    float* __restrict__ S) {
    __shared__ __align__(16) char smem[32768];
    const int b = blockIdx.x;
    const int z = b & 7, r = b >> 3;
    const int by = r >> 4, bx = r & 15;
    const int tid = threadIdx.x;
    const int wave = tid >> 6, lane = tid & 63;
    const int quad = lane >> 4, m16 = lane & 15;
    const int wr = wave >> 1, wc = wave & 1;
    const int row0 = z * 1024 + by * 128;
    const int col0 = bx * 128;

    const int scol = ((lane & 3) ^ ((lane >> 3) & 3)) * 8;
    const int srow = wave * 32 + (lane >> 2);
    const _Float16* agp = qh + (size_t)(row0 + srow) * 512 + scol;
    const _Float16* bgp = kh + (size_t)(z * 2048 + col0 + srow) * 512 + scol;
    const int ldsAoff = wave * 2048;
    const int ldsBoff = 8192 + wave * 2048;

    f32x4 acc[4][4];
#pragma unroll
    for (int mt = 0; mt < 4; ++mt)
#pragma unroll
        for (int nt = 0; nt < 4; ++nt) acc[mt][nt] = (f32x4){0.f, 0.f, 0.f, 0.f};

    auto stage = [&](int i, int buf) {
        char* base = smem + buf * 16384;
        const int k0 = i * 32;
#pragma unroll
        for (int j = 0; j < 2; ++j) {
            glds16(agp + k0 + j * 16 * 512, base + ldsAoff + j * 1024);
            glds16(bgp + k0 + j * 16 * 512, base + ldsBoff + j * 1024);
        }
    };

    const int csw = (quad ^ ((lane >> 1) & 3)) * 16;

    stage(0, 0);
    for (int i = 0; i < 16; ++i) {
        __syncthreads();
        if (i + 1 < 16) stage(i + 1, (i + 1) & 1);
        const char* bb = smem + (i & 1) * 16384;
        const char* pa = bb + (wr * 64 + m16) * 64 + csw;
        const char* pb = bb + 8192 + (wc * 64 + m16) * 64 + csw;
        f16x8 af[4];
#pragma unroll
        for (int mt = 0; mt < 4; ++mt) af[mt] = *(const f16x8*)(pa + mt * 1024);
#pragma unroll
        for (int nt = 0; nt < 4; ++nt) {
            f16x8 bf = *(const f16x8*)(pb + nt * 1024);
#pragma unroll
            for (int mt = 0; mt < 4; ++mt) acc[mt][nt] = MFMA16(af[mt], bf, acc[mt][nt]);
        }
    }
#pragma unroll
    for (int mt = 0; mt < 4; ++mt)
#pragma unroll
        for (int nt = 0; nt < 4; ++nt)
#pragma unroll
            for (int rr = 0; rr < 4; ++rr) {
                int row = row0 + wr * 64 + mt * 16 + quad * 4 + rr;
                int col = col0 + wc * 64 + nt * 16 + m16;
                S[(size_t)row * 2048 + col] = acc[mt][nt][rr];
            }
}

// Row softmax over 2048 cols, fp32 in -> fp16 out (normalized). One block/row.
__global__ __launch_bounds__(256) void softmax_kernel(const float* __restrict__ S,
                                                      _Float16* __restrict__ P) {
    const int row = blockIdx.x;
    const int tid = threadIdx.x;
    const int wave = tid >> 6, lane = tid & 63;
    __shared__ float red[8];

    const float* sp = S + (size_t)row * 2048 + tid * 8;
    float4 x0 = *(const float4*)sp;
    float4 x1 = *(const float4*)(sp + 4);
    float v[8] = {x0.x, x0.y, x0.z, x0.w, x1.x, x1.y, x1.z, x1.w};

    float mx = v[0];
#pragma unroll
    for (int i = 1; i < 8; ++i) mx = fmaxf(mx, v[i]);
#pragma unroll
    for (int off = 32; off > 0; off >>= 1) mx = fmaxf(mx, __shfl_down(mx, off));
    if (lane == 0) red[wave] = mx;
    __syncthreads();
    if (tid == 0) red[4] = fmaxf(fmaxf(red[0], red[1]), fmaxf(red[2], red[3]));
    __syncthreads();
    mx = red[4];

    float e[8];
    float sum = 0.f;
#pragma unroll
    for (int i = 0; i < 8; ++i) {
        e[i] = exp2f((v[i] - mx) * L2E);
        sum += e[i];
    }
#pragma unroll
    for (int off = 32; off > 0; off >>= 1) sum += __shfl_down(sum, off);
    if (lane == 0) red[wave] = sum;
    __syncthreads();
    if (tid == 0) red[5] = red[0] + red[1] + red[2] + red[3];
    __syncthreads();
    float inv = 1.0f / red[5];

    f16x8 ov;
#pragma unroll
    for (int i = 0; i < 8; ++i) ov[i] = (_Float16)(e[i] * inv);
    *(f16x8*)(P + (size_t)row * 2048 + tid * 8) = ov;
}

// PV GEMM (R10 proven form): 64q x 128u tiles, 512 blocks (2 blocks/CU),
// batch-pinned (z = b&7, vt[z] L2-resident), swizzled, __syncthreads-fenced.
__global__ __launch_bounds__(256) void pv_kernel(
    const _Float16* __restrict__ P, const _Float16* __restrict__ vt,
    float* __restrict__ out) {
    __shared__ __align__(16) char smem[24576];
    const int b = blockIdx.x;
    const int z = b & 7, r = b >> 3;
    const int by = r >> 2, bx = r & 3;
    const int tid = threadIdx.x;
    const int wave = tid >> 6, lane = tid & 63;
    const int quad = lane >> 4, m16 = lane & 15;
    const int wr = wave >> 1, wc = wave & 1;
    const int row0 = z * 1024 + by * 64;
    const int col0 = bx * 128;

    const int scol = ((lane & 3) ^ ((lane >> 3) & 3)) * 8;
    const int srowA = wave * 16 + (lane >> 2);
    const int srowB = wave * 32 + (lane >> 2);
    const _Float16* agp = P + (size_t)(row0 + srowA) * 2048 + scol;
    const _Float16* bgp = vt + (size_t)(z * 512 + col0 + srowB) * 2048 + scol;
    const int ldsAoff = wave * 1024;
    const int ldsBoff = 4096 + wave * 2048;

    f32x4 acc[2][4];
#pragma unroll
    for (int mt = 0; mt < 2; ++mt)
#pragma unroll
        for (int nt = 0; nt < 4; ++nt) acc[mt][nt] = (f32x4){0.f, 0.f, 0.f, 0.f};

    auto stage = [&](int i, int buf) {
        char* base = smem + buf * 12288;
        const int k0 = i * 32;
        glds16(agp + k0, base + ldsAoff);
#pragma unroll
        for (int j = 0; j < 2; ++j)
            glds16(bgp + k0 + j * 16 * 2048, base + ldsBoff + j * 1024);
    };

    const int csw = (quad ^ ((lane >> 1) & 3)) * 16;

    stage(0, 0);
    for (int i = 0; i < 64; ++i) {
        __syncthreads();
        if (i + 1 < 64) stage(i + 1, (i + 1) & 1);
        const char* bb = smem + (i & 1) * 12288;
        const char* pa = bb + (wr * 32 + m16) * 64 + csw;
        const char* pb = bb + 4096 + (wc * 64 + m16) * 64 + csw;
        f16x8 af[2];
#pragma unroll
        for (int mt = 0; mt < 2; ++mt) af[mt] = *(const f16x8*)(pa + mt * 1024);
#pragma unroll
        for (int nt = 0; nt < 4; ++nt) {
            f16x8 bf = *(const f16x8*)(pb + nt * 1024);
#pragma unroll
            for (int mt = 0; mt < 2; ++mt) acc[mt][nt] = MFMA16(af[mt], bf, acc[mt][nt]);
        }
    }

#pragma unroll
    for (int mt = 0; mt < 2; ++mt)
#pragma unroll
        for (int nt = 0; nt < 4; ++nt)
#pragma unroll
            for (int rr = 0; rr < 4; ++rr) {
                int row = row0 + wr * 32 + mt * 16 + quad * 4 + rr;
                int col = col0 + wc * 64 + nt * 16 + m16;
                out[(size_t)row * 512 + col] = acc[mt][nt][rr];
            }
}

extern "C" void kernel_launch(void* const* d_in, const int* in_sizes, int n_in,
                              void* d_out, int out_size, void* d_ws, size_t ws_size,
                              hipStream_t stream) {
    const float* enc = (const float*)d_in[0];  // [8,2048,512]
    const float* dec = (const float*)d_in[1];  // [8,1024,512]
    const float* Wq = (const float*)d_in[2];   // [512,512]
    const float* Wk = (const float*)d_in[3];
    const float* Wv = (const float*)d_in[4];
    float* out = (float*)d_out;                // [8,1024,512] fp32

    char* ws = (char*)d_ws;
    _Float16* qh = (_Float16*)(ws);
    _Float16* kh = (_Float16*)(ws + ((size_t)8 << 20));
    _Float16* P = (_Float16*)(ws);                          // aliases qh/kh after score
    _Float16* vt = (_Float16*)(ws + ((size_t)32 << 20));
    float* S = (float*)(ws + ((size_t)48 << 20));
    _Float16* wts = (_Float16*)(ws + ((size_t)56 << 20));   // dead before S written

    dim3 blk(256);
    prep_kernel<<<192, blk, 0, stream>>>(Wq, Wk, Wv, wts);
    proj_kernel<<<1280, blk, 0, stream>>>(dec, enc, wts, qh, kh, vt);
    score_kernel<<<1024, blk, 0, stream>>>(qh, kh, S);
    softmax_kernel<<<8192, blk, 0, stream>>>(S, P);
    pv_kernel<<<512, blk, 0, stream>>>(P, vt, out);
}